// Round 11
// baseline (995.231 us; speedup 1.0000x reference)
//
#include <hip/hip_runtime.h>
#include <stdint.h>

#define B_    128
#define F_    4
#define V_    2048
#define D_    4096
#define DW    64      // D/64 bit-words per (b,f) row
#define VW    32      // V/64 bit-words per d column
#define ITERS 20
#define NKT   16      // K tiles of 128 over V=2048
#define NBLK  1024
#define ESLOT (B_ * F_ * DW)         // u64 words per est slot (256 KB)
#define SSLOT ((size_t)F_ * B_ * V_) // f16 elems per simf slot (2 MB)

typedef _Float16 half8 __attribute__((ext_vector_type(8)));
typedef float   floatx4 __attribute__((ext_vector_type(4)));

// ---- coherent (cross-XCD) STORES: relaxed agent atomics (write side only;
// reads are plain cached loads, legal via single-writer buffer rotation).
__device__ __forceinline__ void cstore32(uint32_t* p, uint32_t v) {
    __hip_atomic_store(p, v, __ATOMIC_RELAXED, __HIP_MEMORY_SCOPE_AGENT);
}

// ---- grid barrier: monotone striped ticket (NO fences, NO resets).
// R7-R10 proven (R8 proved it at NBLK=1024 / 4 blocks/CU co-residency).
// Bounded spins: failure => wrong answer, never a hang.
__device__ __forceinline__ void xbar(int* bar, int gen) {
    __syncthreads();
    if (threadIdx.x == 0) {
        int s = blockIdx.x & 15;
        int t = __hip_atomic_fetch_add(&bar[s * 16], 1, __ATOMIC_RELAXED,
                                       __HIP_MEMORY_SCOPE_AGENT);
        if (t == gen * (NBLK / 16) - 1)
            __hip_atomic_fetch_add(&bar[256], 1, __ATOMIC_RELAXED,
                                   __HIP_MEMORY_SCOPE_AGENT);
        int spins = 0;
        while (__hip_atomic_load(&bar[256], __ATOMIC_RELAXED,
                                 __HIP_MEMORY_SCOPE_AGENT) < gen * 16) {
            __builtin_amdgcn_s_sleep(2);
            if (++spins > (1 << 16)) break;
        }
    }
    __syncthreads();
}

__device__ __forceinline__ void pack16(const float* __restrict__ x,
                                       uint64_t* __restrict__ bits, int t) {
    const float4* p = (const float4*)x + (size_t)t * 4;
    uint32_t m = 0;
    #pragma unroll
    for (int j = 0; j < 4; ++j) {
        float4 v = p[j];
        m |= (__float_as_uint(v.x) >> 31) << (4 * j + 0);
        m |= (__float_as_uint(v.y) >> 31) << (4 * j + 1);
        m |= (__float_as_uint(v.z) >> 31) << (4 * j + 2);
        m |= (__float_as_uint(v.w) >> 31) << (4 * j + 3);
    }
    ((unsigned short*)bits)[t] = (unsigned short)m;
}

// ------------------------------------------------------------------
// Setup: bit-packs (est -> slot 0) + flag/key zeroing (R6-verified).
// ------------------------------------------------------------------
__global__ __launch_bounds__(256) void k_setup(
        const float* __restrict__ cb, const float* __restrict__ inite,
        const float* __restrict__ inputs,
        uint64_t* __restrict__ cb_bits, uint64_t* __restrict__ est0,
        uint64_t* __restrict__ in_bits,
        int* __restrict__ flags, int* __restrict__ keys) {
    int gtid = blockIdx.x * 256 + threadIdx.x;
    const int T = 512 * 256;
    const int ncb = (F_ * V_ * D_) / 16;
    for (int t = gtid; t < ncb; t += T) pack16(cb, cb_bits, t);
    pack16(inite, est0, gtid);
    if (gtid < (B_ * D_) / 16) pack16(inputs, in_bits, gtid);
    if (gtid < 32) flags[gtid] = 0;
    if (gtid < B_ * F_) keys[gtid] = 0;
}

// ------------------------------------------------------------------
// Transpose cb_bits[f][v][dwords] -> cbT[f][d][vwords] (R6-verified).
// ------------------------------------------------------------------
__global__ void k_packT(const uint64_t* __restrict__ cb_bits,
                        uint64_t* __restrict__ cbT) {
    int vw = blockIdx.x, dwg = blockIdx.y, f = blockIdx.z;
    int lane = threadIdx.x & 63;
    int dw = dwg * 4 + (threadIdx.x >> 6);
    uint64_t w = cb_bits[((size_t)f * V_ + vw * 64 + lane) * DW + dw];
    uint64_t r = 0;
    for (int d2 = 0; d2 < 64; ++d2) {
        uint64_t m = __ballot((unsigned)((w >> d2) & 1));
        if (lane == d2) r = m;
    }
    cbT[((size_t)f * D_ + dw * 64 + lane) * VW + vw] = r;
}

// ------------------------------------------------------------------
// Persistent loop v5: 1024 blocks x 256 thr, 32 KB LDS => 4 blocks/CU
// = 16 waves/CU = 4 waves/SIMD (R10 ran 2/SIMD, 48% idle).
// R8's regression at 4/CU is explained by its uncached atomic reads
// (occupancy-insensitive fabric bottleneck) — now removed via R9
// rotation (cached reads) + R10 XCD A-panel sharing.
//   sim:  32v x 32b tile (R8-proven mapping, absmax-verified)
//   gemm: 64m x 32n tile (R7 code, wave 32m x 16n, 1 bfrag/ks)
//   est updated at u32 granularity (byte layout identical).
// ------------------------------------------------------------------
__global__ __launch_bounds__(256, 4) void k_loop(
        const uint64_t* __restrict__ cb_bits, const uint64_t* __restrict__ cbT,
        uint64_t* __restrict__ est_base, const uint64_t* __restrict__ in_bits,
        _Float16* __restrict__ simf_base, int* __restrict__ flags, int* bar) {
    const int bid = blockIdx.x;
    const int tid = threadIdx.x;
    int g = 0;

    __shared__ __align__(16) unsigned char LDSU[32768];   // 32 KB, phase-reused
    __shared__ int bd;

    // sim mapping (R8 verbatim)
    const int s_vt = bid & 63, s_bt = (bid >> 6) & 3, s_f = bid >> 8;
    const int s_v0 = s_vt * 32, s_b0 = s_bt * 32;
    // gemm mapping: XCD (bid&7) fixes (mt,f) so all 128 blocks per XCD
    // share ONE 256 KB simf A-panel (L2-resident); nt spans 0..127.
    const int g_mt = bid & 1, g_f = (bid >> 1) & 3, g_nt = bid >> 3;
    const int g_m0 = g_mt * 64, g_n0 = g_nt * 32;

    const uint64_t SPREAD = 0x1000200040008000ull;    // bit b -> pos 15+16b
    const uint64_t SMASK  = 0x8000800080008000ull;
    const uint64_t PONE   = 0x3C003C003C003C00ull;    // f16 +1.0 x4

    #pragma unroll 1
    for (int i = 0; i < ITERS; ++i) {
        const uint64_t* esti = est_base + (size_t)i * ESLOT;        // read (cached)
        uint64_t*       esto = est_base + (size_t)(i + 1) * ESLOT;  // write (coherent)
        _Float16*       simf = simf_base + (size_t)i * SSLOT;

        // ---- sim: LDS bit-GEMM, tile 32v x 32b ----
        {
            ulonglong2* CB2 = (ulonglong2*)LDSU;            // 16 KB
            ulonglong2* NB2 = (ulonglong2*)(LDSU + 16384);  // 16 KB
            #pragma unroll
            for (int it = 0; it < 4; ++it) {
                int cq = it * 256 + tid;                    // 1024 chunks
                int r = cq >> 5, ch = cq & 31;
                const ulonglong2* src = (const ulonglong2*)(cb_bits + ((size_t)s_f * V_ + s_v0 + r) * DW);
                CB2[r * 32 + (ch ^ (r & 7))] = src[ch];     // read-only: cached
            }
            #pragma unroll
            for (int it = 0; it < 4; ++it) {
                int cq = it * 256 + tid;                    // 1024 chunks
                int r = cq >> 5, ch = cq & 31;
                int b = s_b0 + r;
                const ulonglong2* iv = (const ulonglong2*)(in_bits + (size_t)b * DW);
                const uint64_t* eb = esti + (size_t)b * F_ * DW;
                ulonglong2 i2 = iv[ch];                     // cached
                ulonglong2 e0 = ((const ulonglong2*)(eb + 0 * DW))[ch];  // cached
                ulonglong2 e1 = ((const ulonglong2*)(eb + 1 * DW))[ch];
                ulonglong2 e2 = ((const ulonglong2*)(eb + 2 * DW))[ch];
                ulonglong2 e3 = ((const ulonglong2*)(eb + 3 * DW))[ch];
                uint64_t ex = (s_f == 0) ? e0.x : (s_f == 1) ? e1.x : (s_f == 2) ? e2.x : e3.x;
                uint64_t ey = (s_f == 0) ? e0.y : (s_f == 1) ? e1.y : (s_f == 2) ? e2.y : e3.y;
                ulonglong2 val;
                val.x = i2.x ^ e0.x ^ e1.x ^ e2.x ^ e3.x ^ ex;
                val.y = i2.y ^ e0.y ^ e1.y ^ e2.y ^ e3.y ^ ey;
                NB2[r * 32 + (ch ^ (r & 7))] = val;
            }
            __syncthreads();

            int vv = tid & 15, bb = tid >> 4;
            int svz = vv & 7, sbz = bb & 7;
            int pc[2][2];
            #pragma unroll
            for (int j = 0; j < 2; ++j)
                #pragma unroll
                for (int ii = 0; ii < 2; ++ii) pc[j][ii] = 0;

            #pragma unroll 4
            for (int ch = 0; ch < 32; ++ch) {
                ulonglong2 c[2], n[2];
                #pragma unroll
                for (int ii = 0; ii < 2; ++ii)
                    c[ii] = CB2[(vv + 16 * ii) * 32 + (ch ^ svz)];
                #pragma unroll
                for (int j = 0; j < 2; ++j)
                    n[j] = NB2[(bb + 16 * j) * 32 + (ch ^ sbz)];
                #pragma unroll
                for (int j = 0; j < 2; ++j)
                    #pragma unroll
                    for (int ii = 0; ii < 2; ++ii)
                        pc[j][ii] += __popcll(n[j].x ^ c[ii].x) + __popcll(n[j].y ^ c[ii].y);
            }
            // coherent simf store: pair adjacent lanes (v, v+1) into one u32
            #pragma unroll
            for (int j = 0; j < 2; ++j) {
                int b = s_b0 + bb + 16 * j;
                #pragma unroll
                for (int ii = 0; ii < 2; ++ii) {
                    int v = s_v0 + vv + 16 * ii;
                    union { _Float16 hf; unsigned short us; } cv;
                    cv.hf = (_Float16)(2048 - pc[j][ii]);
                    int other = __shfl_xor((int)cv.us, 1, 64);
                    if (!(vv & 1)) {
                        uint32_t packv = (uint32_t)cv.us | ((uint32_t)other << 16);
                        cstore32((uint32_t*)&simf[((size_t)s_f * B_ + b) * V_ + v], packv);
                    }
                }
            }
        }
        xbar(bar, ++g);

        // ---- gemm: C = sim x (+-1 from cbT); hardsign -> est[i+1] ----
        // tile 64m x 32n; 4 waves, wave tile 32m x 16n (one bfrag/ks).
        {
            int lane = tid & 63, wave = tid >> 6;
            int lrow = lane & 15, lq = lane >> 4;
            int wm = wave & 1, wn = wave >> 1;

            _Float16* As = (_Float16*)LDSU;                 // 16 KB (64 x 128)
            uint64_t* Bb = (uint64_t*)(LDSU + 16384);       // 8 KB (32 x 32 words)
            if (tid == 0) bd = 0;

            const uint64_t* bsrc = cbT + ((size_t)g_f * D_ + g_n0) * VW;
            #pragma unroll
            for (int p = 0; p < 2; ++p) {
                int chunk = p * 256 + tid;                  // 512 chunks
                int dloc = chunk >> 4, cw = chunk & 15;
                ulonglong2 val = *(const ulonglong2*)&bsrc[dloc * VW + cw * 2];  // cached
                *(ulonglong2*)&Bb[dloc * VW + ((cw ^ (dloc & 15)) * 2)] = val;
            }

            const _Float16* Ab = simf + (size_t)g_f * B_ * V_ + (size_t)g_m0 * V_;
            int arow = tid >> 4, acol = tid & 15;
            half8 areg[4];
            #pragma unroll
            for (int p = 0; p < 4; ++p)
                areg[p] = *(const half8*)&Ab[(size_t)(p * 16 + arow) * V_ + acol * 8];  // cached

            floatx4 acc[2] = {};

            #pragma unroll 1
            for (int kt = 0; kt < NKT; ++kt) {
                __syncthreads();   // also covers Bb staging on kt==0
                #pragma unroll
                for (int p = 0; p < 4; ++p)
                    *(half8*)&As[(p * 16 + arow) * 128 + ((acol ^ arow) * 8)] = areg[p];
                if (kt + 1 < NKT) {
                    #pragma unroll
                    for (int p = 0; p < 4; ++p)
                        areg[p] = *(const half8*)&Ab[(size_t)(p * 16 + arow) * V_ + (kt + 1) * 128 + acol * 8];
                }
                __syncthreads();

                int dloc = wn * 16 + lrow;
                ulonglong2 bw = *(const ulonglong2*)&Bb[dloc * VW + ((kt ^ (dloc & 15)) * 2)];
                #pragma unroll
                for (int ks = 0; ks < 4; ++ks) {
                    half8 af[2];
                    #pragma unroll
                    for (int mt2 = 0; mt2 < 2; ++mt2) {
                        int row = wm * 32 + mt2 * 16 + lrow;
                        af[mt2] = *(const half8*)&As[row * 128 + (((ks * 4 + lq) ^ lrow) * 8)];
                    }
                    uint64_t w = (ks < 2) ? bw.x : bw.y;
                    uint32_t byte = (uint32_t)(w >> ((((ks & 1) * 4 + lq)) * 8)) & 0xFFu;
                    union { uint64_t q[2]; half8 h; } bu;
                    bu.q[0] = (((uint64_t)(byte & 0xFu) * SPREAD) & SMASK) ^ PONE;
                    bu.q[1] = (((uint64_t)(byte >> 4)   * SPREAD) & SMASK) ^ PONE;
                    #pragma unroll
                    for (int mt2 = 0; mt2 < 2; ++mt2)
                        acc[mt2] = __builtin_amdgcn_mfma_f32_16x16x32_f16(
                            af[mt2], bu.h, acc[mt2], 0, 0, 0);
                }
            }

            // epilogue: hardsign -> LDS bytes -> bit-pack u32 per row
            __syncthreads();
            unsigned char* S = (unsigned char*)As;          // 64 x 32 bytes
            #pragma unroll
            for (int mt2 = 0; mt2 < 2; ++mt2)
                #pragma unroll
                for (int r = 0; r < 4; ++r) {
                    int row = wm * 32 + mt2 * 16 + lq * 4 + r;   // C/D: row = quad*4+reg
                    int col = wn * 16 + lrow;                    // col = lane&15
                    S[row * 32 + col] = (acc[mt2][r] < 0.0f) ? 1 : 0;  // sign(0)=+1
                }
            __syncthreads();
            if (tid < 64) {
                const uint64_t* Sw = (const uint64_t*)S;
                uint32_t m = 0;
                #pragma unroll
                for (int j = 0; j < 4; ++j) {
                    uint64_t w = Sw[tid * 4 + j];           // 8 bytes of 0/1
                    m |= (uint32_t)((w * 0x0102040810204080ull) >> 56) << (8 * j);
                }
                size_t widx = ((size_t)(g_m0 + tid) * F_ + g_f) * (DW * 2) + g_nt;
                uint32_t old = ((const uint32_t*)esti)[widx];   // cached prev slot
                cstore32((uint32_t*)esto + widx, m);            // coherent next slot
                if (old != m) atomicOr(&bd, 1);
            }
            __syncthreads();
            if (tid == 0 && bd) atomicOr(&flags[i], 1);
        }
        if (i + 1 < ITERS) xbar(bar, ++g);
    }
}

// ------------------------------------------------------------------
// argmax (R6-verified), reads final est slot. grid (vt=64, f=4).
// ------------------------------------------------------------------
__global__ __launch_bounds__(256) void k_argmax(
        const uint64_t* __restrict__ cb_bits,
        const uint64_t* __restrict__ est_bits,
        int* __restrict__ keys) {
    int vt = blockIdx.x, f = blockIdx.y;
    int v0 = vt * 32;
    int tid = threadIdx.x;

    __shared__ __align__(16) ulonglong2 EB2[128 * 32];  // 64 KB
    __shared__ __align__(16) ulonglong2 CBa[32 * 32];   // 16 KB

    #pragma unroll
    for (int it = 0; it < 16; ++it) {
        int cq = it * 256 + tid;
        int r = cq >> 5, ch = cq & 31;
        const ulonglong2* src = (const ulonglong2*)(est_bits + ((size_t)r * F_ + f) * DW);
        EB2[r * 32 + (ch ^ (r & 7))] = src[ch];
    }
    #pragma unroll
    for (int it = 0; it < 4; ++it) {
        int cq = it * 256 + tid;
        int r = cq >> 5, ch = cq & 31;
        const ulonglong2* src = (const ulonglong2*)(cb_bits + ((size_t)f * V_ + v0 + r) * DW);
        CBa[r * 32 + (ch ^ (r & 7))] = src[ch];
    }
    __syncthreads();

    int vv = tid & 15, bb = tid >> 4;
    int svz = vv & 7, sbz = bb & 7;
    int pc[8][2];
    #pragma unroll
    for (int j = 0; j < 8; ++j) { pc[j][0] = 0; pc[j][1] = 0; }

    #pragma unroll 4
    for (int ch = 0; ch < 32; ++ch) {
        ulonglong2 c[2], n[8];
        #pragma unroll
        for (int i = 0; i < 2; ++i)
            c[i] = CBa[(vv + 16 * i) * 32 + (ch ^ svz)];
        #pragma unroll
        for (int j = 0; j < 8; ++j)
            n[j] = EB2[(bb + 16 * j) * 32 + (ch ^ sbz)];
        #pragma unroll
        for (int j = 0; j < 8; ++j)
            #pragma unroll
            for (int i = 0; i < 2; ++i)
                pc[j][i] += __popcll(n[j].x ^ c[i].x) + __popcll(n[j].y ^ c[i].y);
    }

    #pragma unroll
    for (int j = 0; j < 8; ++j) {
        int kj = (int)0x80000000;
        #pragma unroll
        for (int i = 0; i < 2; ++i) {
            int v = v0 + vv + 16 * i;
            int m = 2048 - pc[j][i]; if (m < 0) m = -m;
            int key = (m << 11) | (2047 - v);
            if (key > kj) kj = key;
        }
        #pragma unroll
        for (int s = 1; s < 16; s <<= 1) {
            int o = __shfl_xor(kj, s, 64);
            if (o > kj) kj = o;
        }
        if ((tid & 15) == 0)
            atomicMax(&keys[(size_t)(bb + 16 * j) * F_ + f], kj);
    }
}

__global__ void k_final(const int* __restrict__ keys, const int* __restrict__ flags,
                        int* __restrict__ out) {
    int tid = blockIdx.x * blockDim.x + threadIdx.x;
    if (tid < B_ * F_) out[tid] = 2047 - (keys[tid] & 0x7FF);
    if (tid == 0) {
        int k = ITERS - 1;
        for (int i = 0; i < ITERS; ++i) if (flags[i] == 0) { k = i; break; }
        out[B_ * F_] = k;
    }
}

// ------------------------------------------------------------------
extern "C" void kernel_launch(void* const* d_in, const int* in_sizes, int n_in,
                              void* d_out, int out_size, void* d_ws, size_t ws_size,
                              hipStream_t stream) {
    const float* inputs = (const float*)d_in[0];   // (B, D)
    const float* inite  = (const float*)d_in[1];   // (B, F, D)
    const float* cb     = (const float*)d_in[2];   // (F, V, D)
    int* out = (int*)d_out;                        // 512 outcome + 1 k

    char* ws = (char*)d_ws;
    uint64_t* cb_bits  = (uint64_t*)ws;  ws += (size_t)F_ * V_ * DW * 8;        // 4 MiB
    uint64_t* cbT_bits = (uint64_t*)ws;  ws += (size_t)F_ * D_ * VW * 8;        // 4 MiB
    uint64_t* est_base = (uint64_t*)ws;  ws += (size_t)(ITERS + 1) * ESLOT * 8; // 5.25 MiB (21 slots)
    uint64_t* in_bits  = (uint64_t*)ws;  ws += (size_t)B_ * DW * 8;             // 64 KiB
    _Float16* simf     = (_Float16*)ws;  ws += (size_t)ITERS * SSLOT * 2;       // 40 MiB (20 slots)
    int*      flags    = (int*)ws;       ws += 32 * 4;
    int*      keys     = (int*)ws;       ws += B_ * F_ * 4;
    int*      bar      = (int*)ws;       ws += 2048;

    // bar must be zero at kernel start on EVERY graph replay; the memset is
    // captured in-stream so it re-executes each replay.
    hipMemsetAsync(bar, 0, 2048, stream);

    k_setup<<<512, 256, 0, stream>>>(cb, inite, inputs, cb_bits, est_base,
                                     in_bits, flags, keys);
    k_packT<<<dim3(32, 16, 4), 256, 0, stream>>>(cb_bits, cbT_bits);
    k_loop<<<NBLK, 256, 0, stream>>>(cb_bits, cbT_bits, est_base, in_bits,
                                     simf, flags, bar);
    k_argmax<<<dim3(64, 4), 256, 0, stream>>>(cb_bits,
                                              est_base + (size_t)ITERS * ESLOT, keys);
    k_final<<<2, 256, 0, stream>>>(keys, flags, out);
}

// Round 12
// 845.114 us; speedup vs baseline: 1.1776x; 1.1776x over previous
//
#include <hip/hip_runtime.h>
#include <stdint.h>

#define B_    128
#define F_    4
#define V_    2048
#define D_    4096
#define DW    64      // D/64 bit-words per (b,f) row
#define VW    32      // V/64 bit-words per d column
#define ITERS 20
#define NKT   16      // K tiles of 128 over V=2048
#define NBLK  512
#define ESLOT (B_ * F_ * DW)         // u64 words per est slot (256 KB)
#define SSLOT ((size_t)F_ * B_ * V_) // f16 elems per simf slot (2 MB)

typedef _Float16 half8 __attribute__((ext_vector_type(8)));
typedef float   floatx4 __attribute__((ext_vector_type(4)));

// ---- coherent (cross-XCD) STORES: relaxed agent atomics (write side only;
// reads are plain cached loads, legal via single-writer buffer rotation /
// write-once-then-immutable discipline — audited per buffer).
__device__ __forceinline__ void cstore64(uint64_t* p, uint64_t v) {
    __hip_atomic_store(p, v, __ATOMIC_RELAXED, __HIP_MEMORY_SCOPE_AGENT);
}
__device__ __forceinline__ void cstore32(uint32_t* p, uint32_t v) {
    __hip_atomic_store(p, v, __ATOMIC_RELAXED, __HIP_MEMORY_SCOPE_AGENT);
}

// ---- grid barrier v2: striped ticket + HIERARCHICAL exit.
// Arrivals: 16 stripes -> 1 master (R7-R11 proven). Exit: 8 relay blocks
// (bid<8, one per XCD round-robin) poll the master line; all others poll
// a per-XCD flag line (64 pollers/line, 128B apart) -> no single-line
// oversubscription. Monotone generations, no resets, bounded spins.
__device__ __forceinline__ void xbar(int* bar, int gen) {
    __syncthreads();
    if (threadIdx.x == 0) {
        int s = blockIdx.x & 15;
        int t = __hip_atomic_fetch_add(&bar[s * 16], 1, __ATOMIC_RELAXED,
                                       __HIP_MEMORY_SCOPE_AGENT);
        if (t == gen * (NBLK / 16) - 1)
            __hip_atomic_fetch_add(&bar[256], 1, __ATOMIC_RELAXED,
                                   __HIP_MEMORY_SCOPE_AGENT);
        int spins = 0;
        if (blockIdx.x < 8) {
            while (__hip_atomic_load(&bar[256], __ATOMIC_RELAXED,
                                     __HIP_MEMORY_SCOPE_AGENT) < gen * 16) {
                __builtin_amdgcn_s_sleep(2);
                if (++spins > (1 << 16)) break;
            }
            __hip_atomic_store(&bar[288 + blockIdx.x * 32], gen,
                               __ATOMIC_RELAXED, __HIP_MEMORY_SCOPE_AGENT);
        } else {
            while (__hip_atomic_load(&bar[288 + (blockIdx.x & 7) * 32],
                                     __ATOMIC_RELAXED,
                                     __HIP_MEMORY_SCOPE_AGENT) < gen) {
                __builtin_amdgcn_s_sleep(2);
                if (++spins > (1 << 16)) break;
            }
        }
    }
    __syncthreads();
}

// Pack 32 floats (+-1.0 exactly) -> 32 sign bits -> coherent u32 store.
__device__ __forceinline__ void pack32c(const float* __restrict__ x,
                                        uint32_t* __restrict__ bits, int t) {
    const float4* p = (const float4*)x + (size_t)t * 8;
    uint32_t m = 0;
    #pragma unroll
    for (int j = 0; j < 8; ++j) {
        float4 v = p[j];
        m |= (__float_as_uint(v.x) >> 31) << (4 * j + 0);
        m |= (__float_as_uint(v.y) >> 31) << (4 * j + 1);
        m |= (__float_as_uint(v.z) >> 31) << (4 * j + 2);
        m |= (__float_as_uint(v.w) >> 31) << (4 * j + 3);
    }
    cstore32(&bits[t], m);
}

// ------------------------------------------------------------------
// ONE persistent kernel: setup -> packT -> 20x(sim -> gemm) -> argmax
// -> final, phases separated by xbar. 512 blocks x 256 thr, 64 KB LDS
// (2 blocks/CU co-resident — barrier-safe). Phase algorithms are the
// R5-absmax-verified fused mappings + R9 rotation + R10 XCD remap +
// R10 persistent CB2/Bb staging. New: LUT16 nibble->f16x4 decode (LDS,
// bank-exact broadcast, bit-identical to the multiply-spread path).
// ------------------------------------------------------------------
__global__ __launch_bounds__(256, 2) void k_loop(
        const float* __restrict__ cbf, const float* __restrict__ inite,
        const float* __restrict__ inputs,
        uint64_t* __restrict__ cb_bits, uint64_t* __restrict__ cbT,
        uint64_t* __restrict__ est_base, uint64_t* __restrict__ in_bits,
        _Float16* __restrict__ simf_base, int* __restrict__ flags,
        int* __restrict__ keys, int* __restrict__ out, int* bar) {
    const int bid = blockIdx.x;
    const int tid = threadIdx.x;
    const int gtid = bid * 256 + tid;              // 0..131071
    int g = 0;

    __shared__ __align__(16) unsigned char LDSU[65536];   // 64 KB, phase-reused
    __shared__ uint64_t LUT16[16];
    __shared__ int bd;

    if (tid < 16) {       // nibble -> 4 f16 signs (bit=1 => -1.0)
        uint64_t e = 0;
        #pragma unroll
        for (int j = 0; j < 4; ++j)
            e |= (((tid >> j) & 1) ? 0xBC00ull : 0x3C00ull) << (16 * j);
        LUT16[tid] = e;
    }

    // ============ phase A: bit-pack inputs, zero flags/keys ============
    {
        const int ncb = (F_ * V_ * D_) / 32;       // 262144 -> 2 rounds
        for (int t = gtid; t < ncb; t += NBLK * 256)
            pack32c(cbf, (uint32_t*)cb_bits, t);
        if (gtid < (B_ * F_ * D_) / 32) pack32c(inite, (uint32_t*)est_base, gtid);
        if (gtid < (B_ * D_) / 32)      pack32c(inputs, (uint32_t*)in_bits, gtid);
        if (gtid < 32)      cstore32((uint32_t*)&flags[gtid], 0);
        if (gtid < B_ * F_) cstore32((uint32_t*)&keys[gtid], 0);
    }
    xbar(bar, ++g);

    // ============ phase B: transpose cb bits -> cbT (R5-verified) ======
    {
        int wave = tid >> 6, lane = tid & 63;
        #pragma unroll 1
        for (int s = 0; s < 4; ++s) {
            int u = (bid * 4 + wave) + 2048 * s;   // 8192 (vw,dw,f) units
            int vw = u & 31, dw = (u >> 5) & 63, f = u >> 11;
            uint64_t w = cb_bits[((size_t)f * V_ + vw * 64 + lane) * DW + dw];
            uint64_t r = 0;
            for (int d2 = 0; d2 < 64; ++d2) {
                uint64_t m = __ballot((unsigned)((w >> d2) & 1));
                if (lane == d2) r = m;
            }
            cstore64(&cbT[((size_t)f * D_ + dw * 64 + lane) * VW + vw], r);
        }
    }
    xbar(bar, ++g);

    // ---- XCD-aware index remaps (R10-verified bijections) ----
    const int sgrp = bid & 7;
    const int s_bt = sgrp & 3, s_fhi = sgrp >> 2;
    const int shi  = bid >> 3;
    const int s_vt = shi & 31, s_flo = shi >> 5;
    const int s_f  = s_fhi + 2 * s_flo;
    const int s_v0 = s_vt * 64, s_b0 = s_bt * 32;

    const int ggrp = bid & 7;
    const int g_mt = ggrp & 1, g_f = ggrp >> 1;
    const int g_nt = bid >> 3;
    const int g_m0 = g_mt * 64, g_n0 = g_nt * 64;

    ulonglong2* CB2 = (ulonglong2*)LDSU;              // 32 KB persistent
    ulonglong2* NB2 = (ulonglong2*)(LDSU + 32768);    // 16 KB (sim phase)
    _Float16*   As  = (_Float16*)(LDSU + 32768);      // same 16 KB (gemm phase)
    uint64_t*   Bb  = (uint64_t*)(LDSU + 49152);      // 16 KB persistent

    // ---- stage per-block CONSTANT panels once (after packT barrier) ----
    #pragma unroll
    for (int it = 0; it < 8; ++it) {
        int cq = it * 256 + tid;                      // 2048 chunks
        int r = cq >> 5, ch = cq & 31;
        const ulonglong2* src = (const ulonglong2*)(cb_bits + ((size_t)s_f * V_ + s_v0 + r) * DW);
        CB2[r * 32 + (ch ^ (r & 7))] = src[ch];
    }
    {
        const uint64_t* bsrc = cbT + ((size_t)g_f * D_ + g_n0) * VW;
        #pragma unroll
        for (int p = 0; p < 4; ++p) {
            int chunk = p * 256 + tid;                // 1024 chunks
            int dloc = chunk >> 4, cw = chunk & 15;
            ulonglong2 val = *(const ulonglong2*)&bsrc[dloc * VW + cw * 2];
            *(ulonglong2*)&Bb[dloc * VW + ((cw ^ (dloc & 15)) * 2)] = val;
        }
    }

    // ============ iteration loop ======================================
    #pragma unroll 1
    for (int i = 0; i < ITERS; ++i) {
        const uint64_t* esti = est_base + (size_t)i * ESLOT;        // read (cached)
        uint64_t*       esto = est_base + (size_t)(i + 1) * ESLOT;  // write (coherent)
        _Float16*       simf = simf_base + (size_t)i * SSLOT;

        // ---- sim: LDS bit-GEMM, tile 64v x 32b (CB2 staged) ----
        {
            #pragma unroll
            for (int it = 0; it < 4; ++it) {
                int cq = it * 256 + tid;                    // 1024 chunks
                int r = cq >> 5, ch = cq & 31;
                int b = s_b0 + r;
                const ulonglong2* iv = (const ulonglong2*)(in_bits + (size_t)b * DW);
                const uint64_t* eb = esti + (size_t)b * F_ * DW;
                ulonglong2 i2 = iv[ch];                     // cached
                ulonglong2 e0 = ((const ulonglong2*)(eb + 0 * DW))[ch];  // cached
                ulonglong2 e1 = ((const ulonglong2*)(eb + 1 * DW))[ch];
                ulonglong2 e2 = ((const ulonglong2*)(eb + 2 * DW))[ch];
                ulonglong2 e3 = ((const ulonglong2*)(eb + 3 * DW))[ch];
                uint64_t ex = (s_f == 0) ? e0.x : (s_f == 1) ? e1.x : (s_f == 2) ? e2.x : e3.x;
                uint64_t ey = (s_f == 0) ? e0.y : (s_f == 1) ? e1.y : (s_f == 2) ? e2.y : e3.y;
                ulonglong2 val;
                val.x = i2.x ^ e0.x ^ e1.x ^ e2.x ^ e3.x ^ ex;
                val.y = i2.y ^ e0.y ^ e1.y ^ e2.y ^ e3.y ^ ey;
                NB2[r * 32 + (ch ^ (r & 7))] = val;
            }
            __syncthreads();

            int vv = tid & 15, bb = tid >> 4;
            int svz = vv & 7, sbz = bb & 7;
            int pc[2][4];
            #pragma unroll
            for (int j = 0; j < 2; ++j)
                #pragma unroll
                for (int ii = 0; ii < 4; ++ii) pc[j][ii] = 0;

            #pragma unroll 4
            for (int ch = 0; ch < 32; ++ch) {
                ulonglong2 c[4], n[2];
                #pragma unroll
                for (int ii = 0; ii < 4; ++ii)
                    c[ii] = CB2[(vv + 16 * ii) * 32 + (ch ^ svz)];
                #pragma unroll
                for (int j = 0; j < 2; ++j)
                    n[j] = NB2[(bb + 16 * j) * 32 + (ch ^ sbz)];
                #pragma unroll
                for (int j = 0; j < 2; ++j)
                    #pragma unroll
                    for (int ii = 0; ii < 4; ++ii)
                        pc[j][ii] += __popcll(n[j].x ^ c[ii].x) + __popcll(n[j].y ^ c[ii].y);
            }
            // coherent simf store: pair adjacent lanes (v, v+1) into one u32
            #pragma unroll
            for (int j = 0; j < 2; ++j) {
                int b = s_b0 + bb + 16 * j;
                #pragma unroll
                for (int ii = 0; ii < 4; ++ii) {
                    int v = s_v0 + vv + 16 * ii;
                    union { _Float16 hf; unsigned short us; } cv;
                    cv.hf = (_Float16)(2048 - pc[j][ii]);
                    int other = __shfl_xor((int)cv.us, 1, 64);
                    if (!(vv & 1)) {
                        uint32_t packv = (uint32_t)cv.us | ((uint32_t)other << 16);
                        cstore32((uint32_t*)&simf[((size_t)s_f * B_ + b) * V_ + v], packv);
                    }
                }
            }
        }
        xbar(bar, ++g);

        // ---- gemm: C = sim x (+-1 from Bb); hardsign -> est[i+1] ----
        {
            int lane = tid & 63, wave = tid >> 6;
            int lrow = lane & 15, lq = lane >> 4;
            int wm = wave & 1, wn = wave >> 1;
            if (tid == 0) bd = 0;

            const _Float16* Ab = simf + (size_t)g_f * B_ * V_ + (size_t)g_m0 * V_;
            int arow = tid >> 4, acol = tid & 15;
            half8 areg[4];
            #pragma unroll
            for (int p = 0; p < 4; ++p)
                areg[p] = *(const half8*)&Ab[(size_t)(p * 16 + arow) * V_ + acol * 8];  // cached

            floatx4 acc[2][2] = {};

            #pragma unroll 1
            for (int kt = 0; kt < NKT; ++kt) {
                __syncthreads();
                #pragma unroll
                for (int p = 0; p < 4; ++p)
                    *(half8*)&As[(p * 16 + arow) * 128 + ((acol ^ arow) * 8)] = areg[p];
                if (kt + 1 < NKT) {
                    #pragma unroll
                    for (int p = 0; p < 4; ++p)
                        areg[p] = *(const half8*)&Ab[(size_t)(p * 16 + arow) * V_ + (kt + 1) * 128 + acol * 8];
                }
                __syncthreads();

                ulonglong2 bw[2];
                #pragma unroll
                for (int nt2 = 0; nt2 < 2; ++nt2) {
                    int dloc = wn * 32 + nt2 * 16 + lrow;
                    bw[nt2] = *(const ulonglong2*)&Bb[dloc * VW + ((kt ^ (dloc & 15)) * 2)];
                }
                #pragma unroll
                for (int ks = 0; ks < 4; ++ks) {
                    half8 af[2];
                    #pragma unroll
                    for (int mt2 = 0; mt2 < 2; ++mt2) {
                        int row = wm * 32 + mt2 * 16 + lrow;
                        af[mt2] = *(const half8*)&As[row * 128 + (((ks * 4 + lq) ^ lrow) * 8)];
                    }
                    half8 bfrag[2];
                    #pragma unroll
                    for (int nt2 = 0; nt2 < 2; ++nt2) {
                        uint64_t w = (ks < 2) ? bw[nt2].x : bw[nt2].y;
                        uint32_t byte = (uint32_t)(w >> ((((ks & 1) * 4 + lq)) * 8)) & 0xFFu;
                        union { uint64_t q[2]; half8 h; } bu;
                        bu.q[0] = LUT16[byte & 0xFu];       // bank-exact broadcast
                        bu.q[1] = LUT16[byte >> 4];
                        bfrag[nt2] = bu.h;
                    }
                    #pragma unroll
                    for (int mt2 = 0; mt2 < 2; ++mt2)
                        #pragma unroll
                        for (int nt2 = 0; nt2 < 2; ++nt2)
                            acc[mt2][nt2] = __builtin_amdgcn_mfma_f32_16x16x32_f16(
                                af[mt2], bfrag[nt2], acc[mt2][nt2], 0, 0, 0);
                }
            }

            // epilogue: hardsign -> LDS bytes -> bit-pack u64 per row
            __syncthreads();
            unsigned char* S = (unsigned char*)As;
            #pragma unroll
            for (int mt2 = 0; mt2 < 2; ++mt2)
                #pragma unroll
                for (int nt2 = 0; nt2 < 2; ++nt2)
                    #pragma unroll
                    for (int r = 0; r < 4; ++r) {
                        int row = wm * 32 + mt2 * 16 + lq * 4 + r;   // C/D: row = quad*4+reg
                        int col = wn * 32 + nt2 * 16 + lrow;         // col = lane&15
                        S[row * 64 + col] = (acc[mt2][nt2][r] < 0.0f) ? 1 : 0;  // sign(0)=+1
                    }
            __syncthreads();
            if (tid < 64) {
                const uint64_t* Sw = (const uint64_t*)S;
                uint64_t m = 0;
                #pragma unroll
                for (int j = 0; j < 8; ++j) {
                    uint64_t w = Sw[tid * 8 + j];
                    m |= ((w * 0x0102040810204080ull) >> 56) << (8 * j);
                }
                size_t widx = ((size_t)(g_m0 + tid) * F_ + g_f) * DW + g_nt;
                uint64_t old = esti[widx];                  // cached read of prev slot
                cstore64(&esto[widx], m);                   // coherent write of next slot
                if (old != m) atomicOr(&bd, 1);
            }
            __syncthreads();
            if (tid == 0 && bd) atomicOr(&flags[i], 1);
        }
        xbar(bar, ++g);
    }

    // ============ argmax phase (R5-verified): tile 32v x 64b ===========
    {
        const uint64_t* estF = est_base + (size_t)ITERS * ESLOT;
        int vt = bid & 63, bg = (bid >> 6) & 1, f = bid >> 7;
        int v0 = vt * 32, b0g = bg * 64;
        ulonglong2* EB2 = (ulonglong2*)LDSU;            // 32 KB
        ulonglong2* CBa = (ulonglong2*)(LDSU + 32768);  // 16 KB
        #pragma unroll
        for (int it = 0; it < 8; ++it) {
            int cq = it * 256 + tid;                    // 2048 chunks
            int r = cq >> 5, ch = cq & 31;
            const ulonglong2* src = (const ulonglong2*)(estF + ((size_t)(b0g + r) * F_ + f) * DW);
            EB2[r * 32 + (ch ^ (r & 7))] = src[ch];
        }
        #pragma unroll
        for (int it = 0; it < 4; ++it) {
            int cq = it * 256 + tid;                    // 1024 chunks
            int r = cq >> 5, ch = cq & 31;
            const ulonglong2* src = (const ulonglong2*)(cb_bits + ((size_t)f * V_ + v0 + r) * DW);
            CBa[r * 32 + (ch ^ (r & 7))] = src[ch];
        }
        __syncthreads();

        int vv = tid & 15, bb = tid >> 4;
        int svz = vv & 7, sbz = bb & 7;
        int pc[4][2];
        #pragma unroll
        for (int j = 0; j < 4; ++j) { pc[j][0] = 0; pc[j][1] = 0; }

        #pragma unroll 4
        for (int ch = 0; ch < 32; ++ch) {
            ulonglong2 c[2], n[4];
            #pragma unroll
            for (int ii = 0; ii < 2; ++ii)
                c[ii] = CBa[(vv + 16 * ii) * 32 + (ch ^ svz)];
            #pragma unroll
            for (int j = 0; j < 4; ++j)
                n[j] = EB2[(bb + 16 * j) * 32 + (ch ^ sbz)];
            #pragma unroll
            for (int j = 0; j < 4; ++j)
                #pragma unroll
                for (int ii = 0; ii < 2; ++ii)
                    pc[j][ii] += __popcll(n[j].x ^ c[ii].x) + __popcll(n[j].y ^ c[ii].y);
        }
        #pragma unroll
        for (int j = 0; j < 4; ++j) {
            int kj = (int)0x80000000;
            #pragma unroll
            for (int ii = 0; ii < 2; ++ii) {
                int v = v0 + vv + 16 * ii;
                int m = 2048 - pc[j][ii]; if (m < 0) m = -m;
                int key = (m << 11) | (2047 - v);
                if (key > kj) kj = key;
            }
            #pragma unroll
            for (int s = 1; s < 16; s <<= 1) {
                int o = __shfl_xor(kj, s, 64);
                if (o > kj) kj = o;
            }
            if ((tid & 15) == 0)
                atomicMax(&keys[(size_t)(b0g + bb + 16 * j) * F_ + f], kj);
        }
    }
    xbar(bar, ++g);

    // ============ final outputs =======================================
    if (bid == 0) {
        for (int t = tid; t < B_ * F_; t += 256)
            cstore32((uint32_t*)&out[t], (uint32_t)(2047 - (keys[t] & 0x7FF)));
        if (tid == 0) {
            int k = ITERS - 1;
            for (int i2 = 0; i2 < ITERS; ++i2)
                if (flags[i2] == 0) { k = i2; break; }
            cstore32((uint32_t*)&out[B_ * F_], (uint32_t)k);
        }
    }
}

// ------------------------------------------------------------------
extern "C" void kernel_launch(void* const* d_in, const int* in_sizes, int n_in,
                              void* d_out, int out_size, void* d_ws, size_t ws_size,
                              hipStream_t stream) {
    const float* inputs = (const float*)d_in[0];   // (B, D)
    const float* inite  = (const float*)d_in[1];   // (B, F, D)
    const float* cb     = (const float*)d_in[2];   // (F, V, D)
    int* out = (int*)d_out;                        // 512 outcome + 1 k

    char* ws = (char*)d_ws;
    uint64_t* cb_bits  = (uint64_t*)ws;  ws += (size_t)F_ * V_ * DW * 8;        // 4 MiB
    uint64_t* cbT_bits = (uint64_t*)ws;  ws += (size_t)F_ * D_ * VW * 8;        // 4 MiB
    uint64_t* est_base = (uint64_t*)ws;  ws += (size_t)(ITERS + 1) * ESLOT * 8; // 5.25 MiB (21 slots)
    uint64_t* in_bits  = (uint64_t*)ws;  ws += (size_t)B_ * DW * 8;             // 64 KiB
    _Float16* simf     = (_Float16*)ws;  ws += (size_t)ITERS * SSLOT * 2;       // 40 MiB (20 slots)
    int*      flags    = (int*)ws;       ws += 32 * 4;
    int*      keys     = (int*)ws;       ws += B_ * F_ * 4;
    int*      bar      = (int*)ws;       ws += 4096;

    // bar must be zero at kernel start on EVERY graph replay; the memset is
    // captured in-stream so it re-executes each replay.
    hipMemsetAsync(bar, 0, 4096, stream);

    k_loop<<<NBLK, 256, 0, stream>>>(cb, inite, inputs, cb_bits, cbT_bits,
                                     est_base, in_bits, simf, flags, keys,
                                     out, bar);
}